// Round 5
// baseline (362.809 us; speedup 1.0000x reference)
//
#include <hip/hip_runtime.h>
#include <hip/hip_bf16.h>

#define BB 2
#define NN 384
#define TFD 22
#define POSD 32
#define TPROJ 33
#define CS 256
#define CZ 128
#define PI_F 3.14159265358979323846f

typedef __hip_bfloat16 bf16;
typedef __attribute__((ext_vector_type(8))) short short8;
typedef __attribute__((ext_vector_type(4))) short short4v;
typedef __attribute__((ext_vector_type(4))) float floatx4;

__device__ __forceinline__ float bfbits2f(unsigned short u) {
  unsigned v = ((unsigned)u) << 16;
  float f;
  __builtin_memcpy(&f, &v, 4);
  return f;
}
__device__ __forceinline__ unsigned short f2bf(float x) {
  bf16 h = __float2bfloat16(x);
  unsigned short u;
  __builtin_memcpy(&u, &h, 2);
  return u;
}
__device__ __forceinline__ bool probe_f32(const void* fm) {
  return *(const unsigned*)fm == 0x3F800000u;
}
__device__ __forceinline__ float ldf(const void* p, int j, bool f32) {
  return f32 ? ((const float*)p)[j] : bfbits2f(((const unsigned short*)p)[j]);
}

// ---- ws layout (float units) ----
#define TAB_OFF 0            // 2048*128 (tab incl. all three edge biases)
#define SEQ0_OFF 262144      // 768*256
#define EL_OFF 458752        // 768*128
#define ER_OFF 557056        // 768*128
#define P2_OFF 655360        // 1536 floats of biases/gains
#define WB_OFF 656896        // bf16 (ushort) weight region: 163840 ushorts
#define qBN1 0
#define qBN2 256
#define qGN 512
#define qBEN 768
#define qBE1 1024
#define qBE2 1152
#define qGE 1280
#define qBEE 1408
#define UB_WE1 0
#define UB_WE2 16384
#define UB_WN1 32768
#define UB_WN2 98304

#define NODE8_BLKS 96
#define TAB_BLKS 1024
#define CVT_BLKS 646
#define NODE_BLKS 48
#define JT 64                 // j-rows per edge block
#define EDGE_BLKS (BB * NN * (NN / JT))   // 4608

struct InPtrs { const void* p[28]; };

// ================= prep: node8 + tab + cvt (unchanged, ~6 us) =================
__global__ __launch_bounds__(256) void prep(InPtrs ip, const int* __restrict__ seq_idx,
                                            float* __restrict__ ws) {
  const bool f32 = probe_f32(ip.p[3]);
  const int blk = blockIdx.x;
  const int t = threadIdx.x;
  if (blk < NODE8_BLKS) {
    __shared__ float feat[8][88];
    const int bn0 = blk * 8;
    if (t < 128) {
      const int n = t >> 4, j = t & 15, bn = bn0 + n, b = bn / NN;
      const float fm = ldf(ip.p[3], bn, f32);
      const float idxv = (float)seq_idx[bn];
      const float ang = idxv * PI_F * powf(2056.0f, -(float)j * (1.0f / 16.0f));
      feat[n][j] = sinf(ang);
      feat[n][16 + j] = cosf(ang);
      const float tres = ldf(ip.p[2], b, f32) * fm;
      const float freq = expf(-(logf(10000.0f) * (1.0f / 15.0f)) * (float)j);
      feat[n][54 + j] = sinf(tres * freq);
      feat[n][70 + j] = cosf(tres * freq);
      if (j == 0) feat[n][86] = fm;
    }
    if (t < 176) {
      const int n = t / TFD, j = t - n * TFD;
      feat[n][32 + j] = ldf(ip.p[1], (bn0 + n) * TFD + j, f32);
    }
    __syncthreads();
    {
      const int c = t;
      const float bias = ldf(ip.p[5], c, f32) + ldf(ip.p[7], c, f32) + ldf(ip.p[9], c, f32);
      float acc[8];
#pragma unroll
      for (int n = 0; n < 8; ++n) acc[n] = bias;
      if (f32) {
        const float* w = (const float*)ip.p[4] + c * POSD;
#pragma unroll
        for (int k = 0; k < POSD; ++k) { const float wv = w[k];
#pragma unroll
          for (int n = 0; n < 8; ++n) acc[n] += feat[n][k] * wv; }
        const float* w2 = (const float*)ip.p[6] + c * TFD;
#pragma unroll
        for (int k = 0; k < TFD; ++k) { const float wv = w2[k];
#pragma unroll
          for (int n = 0; n < 8; ++n) acc[n] += feat[n][32 + k] * wv; }
        const float* w3 = (const float*)ip.p[8] + c * TPROJ;
#pragma unroll
        for (int k = 0; k < TPROJ; ++k) { const float wv = w3[k];
#pragma unroll
          for (int n = 0; n < 8; ++n) acc[n] += feat[n][54 + k] * wv; }
      } else {
        const unsigned short* w = (const unsigned short*)ip.p[4] + c * POSD;
#pragma unroll
        for (int k = 0; k < POSD; ++k) { const float wv = bfbits2f(w[k]);
#pragma unroll
          for (int n = 0; n < 8; ++n) acc[n] += feat[n][k] * wv; }
        const unsigned short* w2 = (const unsigned short*)ip.p[6] + c * TFD;
#pragma unroll
        for (int k = 0; k < TFD; ++k) { const float wv = bfbits2f(w2[k]);
#pragma unroll
          for (int n = 0; n < 8; ++n) acc[n] += feat[n][32 + k] * wv; }
        const unsigned short* w3 = (const unsigned short*)ip.p[8] + c * TPROJ;
#pragma unroll
        for (int k = 0; k < TPROJ; ++k) { const float wv = bfbits2f(w3[k]);
#pragma unroll
          for (int n = 0; n < 8; ++n) acc[n] += feat[n][54 + k] * wv; }
      }
#pragma unroll
      for (int n = 0; n < 8; ++n) ws[SEQ0_OFF + (bn0 + n) * CS + c] = acc[n];
    }
    {
      const int isR = t >> 7;
      const int c = t & 127;
      const int o1 = isR ? TFD : 0, o2 = isR ? TPROJ : 0;
      const int dst = isR ? ER_OFF : EL_OFF;
      float acc[8];
#pragma unroll
      for (int n = 0; n < 8; ++n) acc[n] = 0.0f;
      if (f32) {
        const float* w = (const float*)ip.p[18] + c * (2 * TFD) + o1;
#pragma unroll
        for (int k = 0; k < TFD; ++k) { const float wv = w[k];
#pragma unroll
          for (int n = 0; n < 8; ++n) acc[n] += feat[n][32 + k] * wv; }
        const float* w2 = (const float*)ip.p[20] + c * (2 * TPROJ) + o2;
#pragma unroll
        for (int k = 0; k < TPROJ; ++k) { const float wv = w2[k];
#pragma unroll
          for (int n = 0; n < 8; ++n) acc[n] += feat[n][54 + k] * wv; }
      } else {
        const unsigned short* w = (const unsigned short*)ip.p[18] + c * (2 * TFD) + o1;
#pragma unroll
        for (int k = 0; k < TFD; ++k) { const float wv = bfbits2f(w[k]);
#pragma unroll
          for (int n = 0; n < 8; ++n) acc[n] += feat[n][32 + k] * wv; }
        const unsigned short* w2 = (const unsigned short*)ip.p[20] + c * (2 * TPROJ) + o2;
#pragma unroll
        for (int k = 0; k < TPROJ; ++k) { const float wv = bfbits2f(w2[k]);
#pragma unroll
          for (int n = 0; n < 8; ++n) acc[n] += feat[n][54 + k] * wv; }
      }
#pragma unroll
      for (int n = 0; n < 8; ++n) ws[dst + (bn0 + n) * CZ + c] = acc[n];
    }
  } else if (blk < NODE8_BLKS + TAB_BLKS) {
    __shared__ float spe[2][POSD];
    const int r0 = (blk - NODE8_BLKS) * 2;
    const int rr = t >> 7, c = t & 127;
    if (c < 16) {
      float ang = (float)(r0 + rr - 1024) * PI_F * powf(2056.0f, -(float)c * (1.0f / 16.0f));
      spe[rr][c] = sinf(ang);
      spe[rr][c + 16] = cosf(ang);
    }
    __syncthreads();
    float acc = ldf(ip.p[17], c, f32) + ldf(ip.p[19], c, f32) + ldf(ip.p[21], c, f32);
    if (f32) {
      const float* w = (const float*)ip.p[16] + c * POSD;
#pragma unroll
      for (int k = 0; k < POSD; ++k) acc += spe[rr][k] * w[k];
    } else {
      const unsigned short* w = (const unsigned short*)ip.p[16] + c * POSD;
#pragma unroll
      for (int k = 0; k < POSD; ++k) acc += spe[rr][k] * bfbits2f(w[k]);
    }
    ws[TAB_OFF + (r0 + rr) * CZ + c] = acc;
  } else {
    const int idx = (blk - NODE8_BLKS - TAB_BLKS) * 256 + t;
    if (idx < 1536) {
      int src, off;
      if (idx < 256)       { src = 11; off = idx; }
      else if (idx < 512)  { src = 13; off = idx - 256; }
      else if (idx < 768)  { src = 14; off = idx - 512; }
      else if (idx < 1024) { src = 15; off = idx - 768; }
      else if (idx < 1152) { src = 23; off = idx - 1024; }
      else if (idx < 1280) { src = 25; off = idx - 1152; }
      else if (idx < 1408) { src = 26; off = idx - 1280; }
      else                 { src = 27; off = idx - 1408; }
      ws[P2_OFF + idx] = ldf(ip.p[src], off, f32);
    } else {
      const int j = idx - 1536;
      int src, loc;
      if (j < 16384)      { src = 22; loc = j; }
      else if (j < 32768) { src = 24; loc = j - 16384; }
      else if (j < 98304) { src = 10; loc = j - 32768; }
      else                { src = 12; loc = j - 98304; }
      const void* sp = ip.p[src];
      unsigned short* wb = (unsigned short*)(ws + WB_OFF);
      wb[j] = f32 ? f2bf(((const float*)sp)[loc]) : ((const unsigned short*)sp)[loc];
    }
  }
}

// ================= node MLP: standalone, 48 blocks x 16 rows (unchanged) ==========
struct SMemN {
  unsigned short A0[16][CS + 8];
  unsigned short A1[16][CS + 8];
  float O[16][CS + 4];
  float Red[16][16];
  float RedQ[16][16];
  float Mu[16];
  float Rs[16];
};

__global__ __launch_bounds__(256) void node_mfma(const float* __restrict__ ws,
                                                 const void* __restrict__ fmraw,
                                                 void* __restrict__ outv) {
  __shared__ __align__(16) SMemN sm;
  const int t = threadIdx.x;
  const int wave = t >> 6, lane = t & 63, quad = lane >> 4, l16 = lane & 15;
  const float* P2 = ws + P2_OFF;
  const unsigned short* WB = (const unsigned short*)(ws + WB_OFF);
  const bool f32o = probe_f32(fmraw);
  const int row0 = blockIdx.x * 16;
  const unsigned short* W1 = WB + UB_WN1;
  const unsigned short* W2 = WB + UB_WN2;
  const float* seq0 = ws + SEQ0_OFF;
#pragma unroll
  for (int r = 0; r < 16; ++r)
    sm.A0[r][t] = f2bf(fmaxf(seq0[(row0 + r) * CS + t], 0.0f));
  __syncthreads();
  short8 af[8];
  floatx4 acc[4];
#pragma unroll
  for (int ks = 0; ks < 8; ++ks) af[ks] = *(const short8*)&sm.A0[l16][ks * 32 + quad * 8];
#pragma unroll
  for (int n = 0; n < 4; ++n) acc[n] = (floatx4){0.f, 0.f, 0.f, 0.f};
#pragma unroll
  for (int ntl = 0; ntl < 4; ++ntl) {
    const int n0 = wave * 64 + ntl * 16;
#pragma unroll
    for (int ks = 0; ks < 8; ++ks) {
      short8 bfr = *(const short8*)&W1[(n0 + l16) * CS + ks * 32 + quad * 8];
      acc[ntl] = __builtin_amdgcn_mfma_f32_16x16x32_bf16(af[ks], bfr, acc[ntl], 0, 0, 0);
    }
  }
#pragma unroll
  for (int ntl = 0; ntl < 4; ++ntl) {
    const int n0 = wave * 64 + ntl * 16;
    const float b1v = P2[qBN1 + n0 + l16];
#pragma unroll
    for (int i = 0; i < 4; ++i)
      sm.A1[quad * 4 + i][n0 + l16] = f2bf(fmaxf(acc[ntl][i] + b1v, 0.0f));
  }
  __syncthreads();
#pragma unroll
  for (int ks = 0; ks < 8; ++ks) af[ks] = *(const short8*)&sm.A1[l16][ks * 32 + quad * 8];
#pragma unroll
  for (int n = 0; n < 4; ++n) acc[n] = (floatx4){0.f, 0.f, 0.f, 0.f};
#pragma unroll
  for (int ntl = 0; ntl < 4; ++ntl) {
    const int n0 = wave * 64 + ntl * 16;
#pragma unroll
    for (int ks = 0; ks < 8; ++ks) {
      short8 bfr = *(const short8*)&W2[(n0 + l16) * CS + ks * 32 + quad * 8];
      acc[ntl] = __builtin_amdgcn_mfma_f32_16x16x32_bf16(af[ks], bfr, acc[ntl], 0, 0, 0);
    }
  }
#pragma unroll
  for (int ntl = 0; ntl < 4; ++ntl) {
    const int n0 = wave * 64 + ntl * 16;
    const float b2v = P2[qBN2 + n0 + l16];
#pragma unroll
    for (int i = 0; i < 4; ++i)
      sm.O[quad * 4 + i][n0 + l16] = acc[ntl][i] + b2v;
  }
  __syncthreads();
  {
    const int r = t >> 4, seg = t & 15;
    float s = 0.f, q = 0.f;
#pragma unroll
    for (int k = 0; k < 16; ++k) { float v = sm.O[r][seg * 16 + k]; s += v; q += v * v; }
    sm.Red[r][seg] = s;
    sm.RedQ[r][seg] = q;
  }
  __syncthreads();
  if (t < 16) {
    float s = 0.f, q = 0.f;
#pragma unroll
    for (int k = 0; k < 16; ++k) { s += sm.Red[t][k]; q += sm.RedQ[t][k]; }
    float mu = s * (1.0f / CS);
    float var = q * (1.0f / CS) - mu * mu;
    sm.Mu[t] = mu;
    sm.Rs[t] = rsqrtf(var + 1e-5f);
  }
  __syncthreads();
  {
    const float g = P2[qGN + t], be = P2[qBEN + t];
    if (f32o) {
      float* o = (float*)outv;
#pragma unroll
      for (int r = 0; r < 16; ++r)
        o[(size_t)(row0 + r) * CS + t] = (sm.O[r][t] - sm.Mu[r]) * sm.Rs[r] * g + be;
    } else {
      bf16* o = (bf16*)outv;
#pragma unroll
      for (int r = 0; r < 16; ++r)
        o[(size_t)(row0 + r) * CS + t] =
            __float2bfloat16((sm.O[r][t] - sm.Mu[r]) * sm.Rs[r] * g + be);
    }
  }
}

// ============== edge MLP: 4608 blocks, 64-row tile, ONE barrier, 17.4 KB LDS ==========
// Wave w owns rows w*16..w*16+15 end-to-end (layer1, transpose-in-own-A0-rows, layer2,
// wave-local LN, store from accumulators). Weights streamed from L2 (same addresses
// across all blocks -> broadcast). High occupancy is the goal: LDS 17.4 KB (9 blk/CU),
// VGPR capped ~85 via __launch_bounds__(256,6) -> ~24 waves/CU vs r0's 16.
__global__ __launch_bounds__(256, 6) void edge64(const int* __restrict__ seq_idx,
                                                 const float* __restrict__ ws,
                                                 const void* __restrict__ fmraw,
                                                 void* __restrict__ outv) {
  __shared__ __align__(16) unsigned short A0[JT][CZ + 8];  // 64 x 136 x 2B = 17408 B
  const int t = threadIdx.x;
  const int wave = t >> 6, lane = t & 63, quad = lane >> 4, l16 = lane & 15;
  const float* P2 = ws + P2_OFF;
  const unsigned short* WB = (const unsigned short*)(ws + WB_OFF);
  const unsigned short* W1 = WB + UB_WE1;
  const unsigned short* W2 = WB + UB_WE2;
  const float* tab = ws + TAB_OFF;
  const bool f32o = probe_f32(fmraw);

  const int bid = blockIdx.x;
  const int jt = bid % (NN / JT);
  const int rem = bid / (NN / JT);
  const int irow = rem % NN;
  const int b = rem / NN;
  const int j0 = jt * JT;
  const int idx_i = seq_idx[b * NN + irow];
  const float* el = ws + EL_OFF + (size_t)(b * NN + irow) * CZ;
  const float* eRb = ws + ER_OFF + (size_t)b * NN * CZ;
  const size_t base0 = ((size_t)(b * NN + irow) * NN) * CZ;

  // ---- stage A0 = bf16(relu(tab[rel] + eL + eR)), coalesced float4 ----
  {
    const int c4 = (t & 31) * 4;
    const int rg = t >> 5;  // 0..7
    const floatx4 eLv = *(const floatx4*)&el[c4];
#pragma unroll
    for (int rr = 0; rr < 8; ++rr) {
      const int r = rg * 8 + rr;
      int rel = idx_i - seq_idx[b * NN + j0 + r] + 1024;
      rel = min(max(rel, 0), 2047);
      const floatx4 tv = *(const floatx4*)&tab[(size_t)rel * CZ + c4];
      const floatx4 ev = *(const floatx4*)&eRb[(size_t)(j0 + r) * CZ + c4];
      short4v sv;
#pragma unroll
      for (int u = 0; u < 4; ++u) sv[u] = (short)f2bf(fmaxf(tv[u] + ev[u] + eLv[u], 0.0f));
      *(short4v*)&A0[r][c4] = sv;
    }
  }
  __syncthreads();  // the ONLY barrier

  // ---- layer 1: A from own rows, B streamed from L2 ----
  short8 af[4];
#pragma unroll
  for (int ks = 0; ks < 4; ++ks)
    af[ks] = *(const short8*)&A0[wave * 16 + l16][ks * 32 + quad * 8];
  floatx4 acc[8];
#pragma unroll
  for (int n = 0; n < 8; ++n) acc[n] = (floatx4){0.f, 0.f, 0.f, 0.f};
#pragma unroll
  for (int ntl = 0; ntl < 8; ++ntl) {
    const unsigned short* wrow = W1 + (size_t)(ntl * 16 + l16) * CZ;
#pragma unroll
    for (int ks = 0; ks < 4; ++ks) {
      const short8 bfr = *(const short8*)&wrow[ks * 32 + quad * 8];
      acc[ntl] = __builtin_amdgcn_mfma_f32_16x16x32_bf16(af[ks], bfr, acc[ntl], 0, 0, 0);
    }
  }

  // ---- bias+relu -> transpose through the wave's OWN A0 rows (no barrier needed:
  //      all af reads precede these writes by data dependence; same-wave DS is in-order)
  unsigned short* scr = &A0[wave * 16][0];
#pragma unroll
  for (int ntl = 0; ntl < 8; ++ntl) {
    const float b1v = P2[qBE1 + ntl * 16 + l16];
#pragma unroll
    for (int i = 0; i < 4; ++i)
      scr[(quad * 4 + i) * (CZ + 8) + ntl * 16 + l16] = f2bf(fmaxf(acc[ntl][i] + b1v, 0.0f));
  }
  short8 af2[4];
#pragma unroll
  for (int ks = 0; ks < 4; ++ks)
    af2[ks] = *(const short8*)&scr[l16 * (CZ + 8) + ks * 32 + quad * 8];

  // ---- layer 2 ----
#pragma unroll
  for (int n = 0; n < 8; ++n) acc[n] = (floatx4){0.f, 0.f, 0.f, 0.f};
#pragma unroll
  for (int ntl = 0; ntl < 8; ++ntl) {
    const unsigned short* wrow = W2 + (size_t)(ntl * 16 + l16) * CZ;
#pragma unroll
    for (int ks = 0; ks < 4; ++ks) {
      const short8 bfr = *(const short8*)&wrow[ks * 32 + quad * 8];
      acc[ntl] = __builtin_amdgcn_mfma_f32_16x16x32_bf16(af2[ks], bfr, acc[ntl], 0, 0, 0);
    }
  }

  // ---- bias + wave-local LayerNorm (16-lane quad shuffle) + store from accumulators ----
  float s[4] = {0.f, 0.f, 0.f, 0.f}, q[4] = {0.f, 0.f, 0.f, 0.f};
#pragma unroll
  for (int ntl = 0; ntl < 8; ++ntl) {
    const float b2v = P2[qBE2 + ntl * 16 + l16];
#pragma unroll
    for (int i = 0; i < 4; ++i) {
      const float v = acc[ntl][i] + b2v;
      acc[ntl][i] = v;
      s[i] += v;
      q[i] += v * v;
    }
  }
#pragma unroll
  for (int m = 1; m <= 8; m <<= 1) {
#pragma unroll
    for (int i = 0; i < 4; ++i) {
      s[i] += __shfl_xor(s[i], m);
      q[i] += __shfl_xor(q[i], m);
    }
  }
  float mu[4], rs[4];
#pragma unroll
  for (int i = 0; i < 4; ++i) {
    mu[i] = s[i] * (1.0f / CZ);
    rs[i] = rsqrtf(q[i] * (1.0f / CZ) - mu[i] * mu[i] + 1e-5f);
  }
  const int jrow = j0 + wave * 16 + quad * 4;
  if (f32o) {
    float* o = (float*)outv + (size_t)BB * NN * CS;
#pragma unroll
    for (int ntl = 0; ntl < 8; ++ntl) {
      const float g = P2[qGE + ntl * 16 + l16];
      const float be = P2[qBEE + ntl * 16 + l16];
#pragma unroll
      for (int i = 0; i < 4; ++i)
        o[base0 + (size_t)(jrow + i) * CZ + ntl * 16 + l16] =
            (acc[ntl][i] - mu[i]) * rs[i] * g + be;
    }
  } else {
    bf16* o = (bf16*)outv + (size_t)BB * NN * CS;
#pragma unroll
    for (int ntl = 0; ntl < 8; ++ntl) {
      const float g = P2[qGE + ntl * 16 + l16];
      const float be = P2[qBEE + ntl * 16 + l16];
#pragma unroll
      for (int i = 0; i < 4; ++i)
        o[base0 + (size_t)(jrow + i) * CZ + ntl * 16 + l16] =
            __float2bfloat16((acc[ntl][i] - mu[i]) * rs[i] * g + be);
    }
  }
}

extern "C" void kernel_launch(void* const* d_in, const int* in_sizes, int n_in,
                              void* d_out, int out_size, void* d_ws, size_t ws_size,
                              hipStream_t stream) {
  (void)in_sizes; (void)n_in; (void)out_size; (void)ws_size;
  const int* seq_idx = (const int*)d_in[0];
  float* ws = (float*)d_ws;
  InPtrs ip;
  for (int i = 0; i < 28; ++i) ip.p[i] = d_in[i];
  hipLaunchKernelGGL(prep, dim3(NODE8_BLKS + TAB_BLKS + CVT_BLKS), dim3(256), 0, stream,
                     ip, seq_idx, ws);
  hipLaunchKernelGGL(node_mfma, dim3(NODE_BLKS), dim3(256), 0, stream, ws, d_in[3], d_out);
  hipLaunchKernelGGL(edge64, dim3(EDGE_BLKS), dim3(256), 0, stream, seq_idx, ws, d_in[3], d_out);
}

// Round 6
// 256.993 us; speedup vs baseline: 1.4117x; 1.4117x over previous
//
#include <hip/hip_runtime.h>
#include <hip/hip_bf16.h>

#define BB 2
#define NN 384
#define TFD 22
#define POSD 32
#define TPROJ 33
#define CS 256
#define CZ 128
#define PI_F 3.14159265358979323846f

typedef __hip_bfloat16 bf16;
typedef __attribute__((ext_vector_type(8))) short short8;
typedef __attribute__((ext_vector_type(4))) short short4v;
typedef __attribute__((ext_vector_type(4))) float floatx4;

__device__ __forceinline__ float bfbits2f(unsigned short u) {
  unsigned v = ((unsigned)u) << 16;
  float f;
  __builtin_memcpy(&f, &v, 4);
  return f;
}
__device__ __forceinline__ unsigned short f2bf(float x) {
  bf16 h = __float2bfloat16(x);
  unsigned short u;
  __builtin_memcpy(&u, &h, 2);
  return u;
}
__device__ __forceinline__ bool probe_f32(const void* fm) {
  return *(const unsigned*)fm == 0x3F800000u;
}
__device__ __forceinline__ float ldf(const void* p, int j, bool f32) {
  return f32 ? ((const float*)p)[j] : bfbits2f(((const unsigned short*)p)[j]);
}

// ---- ws layout (float units) ----
#define TAB_OFF 0            // 2048*128 (tab incl. all three edge biases)
#define SEQ0_OFF 262144      // 768*256
#define EL_OFF 458752        // 768*128
#define ER_OFF 557056        // 768*128
#define P2_OFF 655360        // 1536 floats of biases/gains
#define WB_OFF 656896        // bf16 (ushort) weight region: 163840 ushorts
#define qBN1 0
#define qBN2 256
#define qGN 512
#define qBEN 768
#define qBE1 1024
#define qBE2 1152
#define qGE 1280
#define qBEE 1408
#define UB_WE1 0
#define UB_WE2 16384
#define UB_WN1 32768
#define UB_WN2 98304

#define NODE8_BLKS 96
#define TAB_BLKS 1024
#define CVT_BLKS 646
#define NODE_BLKS 48

struct InPtrs { const void* p[28]; };

// ================= prep: node8 + tab + cvt (verified r3-r5) =================
__global__ __launch_bounds__(256) void prep(InPtrs ip, const int* __restrict__ seq_idx,
                                            float* __restrict__ ws) {
  const bool f32 = probe_f32(ip.p[3]);
  const int blk = blockIdx.x;
  const int t = threadIdx.x;
  if (blk < NODE8_BLKS) {
    __shared__ float feat[8][88];
    const int bn0 = blk * 8;
    if (t < 128) {
      const int n = t >> 4, j = t & 15, bn = bn0 + n, b = bn / NN;
      const float fm = ldf(ip.p[3], bn, f32);
      const float idxv = (float)seq_idx[bn];
      const float ang = idxv * PI_F * powf(2056.0f, -(float)j * (1.0f / 16.0f));
      feat[n][j] = sinf(ang);
      feat[n][16 + j] = cosf(ang);
      const float tres = ldf(ip.p[2], b, f32) * fm;
      const float freq = expf(-(logf(10000.0f) * (1.0f / 15.0f)) * (float)j);
      feat[n][54 + j] = sinf(tres * freq);
      feat[n][70 + j] = cosf(tres * freq);
      if (j == 0) feat[n][86] = fm;
    }
    if (t < 176) {
      const int n = t / TFD, j = t - n * TFD;
      feat[n][32 + j] = ldf(ip.p[1], (bn0 + n) * TFD + j, f32);
    }
    __syncthreads();
    {
      const int c = t;
      const float bias = ldf(ip.p[5], c, f32) + ldf(ip.p[7], c, f32) + ldf(ip.p[9], c, f32);
      float acc[8];
#pragma unroll
      for (int n = 0; n < 8; ++n) acc[n] = bias;
      if (f32) {
        const float* w = (const float*)ip.p[4] + c * POSD;
#pragma unroll
        for (int k = 0; k < POSD; ++k) { const float wv = w[k];
#pragma unroll
          for (int n = 0; n < 8; ++n) acc[n] += feat[n][k] * wv; }
        const float* w2 = (const float*)ip.p[6] + c * TFD;
#pragma unroll
        for (int k = 0; k < TFD; ++k) { const float wv = w2[k];
#pragma unroll
          for (int n = 0; n < 8; ++n) acc[n] += feat[n][32 + k] * wv; }
        const float* w3 = (const float*)ip.p[8] + c * TPROJ;
#pragma unroll
        for (int k = 0; k < TPROJ; ++k) { const float wv = w3[k];
#pragma unroll
          for (int n = 0; n < 8; ++n) acc[n] += feat[n][54 + k] * wv; }
      } else {
        const unsigned short* w = (const unsigned short*)ip.p[4] + c * POSD;
#pragma unroll
        for (int k = 0; k < POSD; ++k) { const float wv = bfbits2f(w[k]);
#pragma unroll
          for (int n = 0; n < 8; ++n) acc[n] += feat[n][k] * wv; }
        const unsigned short* w2 = (const unsigned short*)ip.p[6] + c * TFD;
#pragma unroll
        for (int k = 0; k < TFD; ++k) { const float wv = bfbits2f(w2[k]);
#pragma unroll
          for (int n = 0; n < 8; ++n) acc[n] += feat[n][32 + k] * wv; }
        const unsigned short* w3 = (const unsigned short*)ip.p[8] + c * TPROJ;
#pragma unroll
        for (int k = 0; k < TPROJ; ++k) { const float wv = bfbits2f(w3[k]);
#pragma unroll
          for (int n = 0; n < 8; ++n) acc[n] += feat[n][54 + k] * wv; }
      }
#pragma unroll
      for (int n = 0; n < 8; ++n) ws[SEQ0_OFF + (bn0 + n) * CS + c] = acc[n];
    }
    {
      const int isR = t >> 7;
      const int c = t & 127;
      const int o1 = isR ? TFD : 0, o2 = isR ? TPROJ : 0;
      const int dst = isR ? ER_OFF : EL_OFF;
      float acc[8];
#pragma unroll
      for (int n = 0; n < 8; ++n) acc[n] = 0.0f;
      if (f32) {
        const float* w = (const float*)ip.p[18] + c * (2 * TFD) + o1;
#pragma unroll
        for (int k = 0; k < TFD; ++k) { const float wv = w[k];
#pragma unroll
          for (int n = 0; n < 8; ++n) acc[n] += feat[n][32 + k] * wv; }
        const float* w2 = (const float*)ip.p[20] + c * (2 * TPROJ) + o2;
#pragma unroll
        for (int k = 0; k < TPROJ; ++k) { const float wv = w2[k];
#pragma unroll
          for (int n = 0; n < 8; ++n) acc[n] += feat[n][54 + k] * wv; }
      } else {
        const unsigned short* w = (const unsigned short*)ip.p[18] + c * (2 * TFD) + o1;
#pragma unroll
        for (int k = 0; k < TFD; ++k) { const float wv = bfbits2f(w[k]);
#pragma unroll
          for (int n = 0; n < 8; ++n) acc[n] += feat[n][32 + k] * wv; }
        const unsigned short* w2 = (const unsigned short*)ip.p[20] + c * (2 * TPROJ) + o2;
#pragma unroll
        for (int k = 0; k < TPROJ; ++k) { const float wv = bfbits2f(w2[k]);
#pragma unroll
          for (int n = 0; n < 8; ++n) acc[n] += feat[n][54 + k] * wv; }
      }
#pragma unroll
      for (int n = 0; n < 8; ++n) ws[dst + (bn0 + n) * CZ + c] = acc[n];
    }
  } else if (blk < NODE8_BLKS + TAB_BLKS) {
    __shared__ float spe[2][POSD];
    const int r0 = (blk - NODE8_BLKS) * 2;
    const int rr = t >> 7, c = t & 127;
    if (c < 16) {
      float ang = (float)(r0 + rr - 1024) * PI_F * powf(2056.0f, -(float)c * (1.0f / 16.0f));
      spe[rr][c] = sinf(ang);
      spe[rr][c + 16] = cosf(ang);
    }
    __syncthreads();
    float acc = ldf(ip.p[17], c, f32) + ldf(ip.p[19], c, f32) + ldf(ip.p[21], c, f32);
    if (f32) {
      const float* w = (const float*)ip.p[16] + c * POSD;
#pragma unroll
      for (int k = 0; k < POSD; ++k) acc += spe[rr][k] * w[k];
    } else {
      const unsigned short* w = (const unsigned short*)ip.p[16] + c * POSD;
#pragma unroll
      for (int k = 0; k < POSD; ++k) acc += spe[rr][k] * bfbits2f(w[k]);
    }
    ws[TAB_OFF + (r0 + rr) * CZ + c] = acc;
  } else {
    const int idx = (blk - NODE8_BLKS - TAB_BLKS) * 256 + t;
    if (idx < 1536) {
      int src, off;
      if (idx < 256)       { src = 11; off = idx; }
      else if (idx < 512)  { src = 13; off = idx - 256; }
      else if (idx < 768)  { src = 14; off = idx - 512; }
      else if (idx < 1024) { src = 15; off = idx - 768; }
      else if (idx < 1152) { src = 23; off = idx - 1024; }
      else if (idx < 1280) { src = 25; off = idx - 1152; }
      else if (idx < 1408) { src = 26; off = idx - 1280; }
      else                 { src = 27; off = idx - 1408; }
      ws[P2_OFF + idx] = ldf(ip.p[src], off, f32);
    } else {
      const int j = idx - 1536;
      int src, loc;
      if (j < 16384)      { src = 22; loc = j; }
      else if (j < 32768) { src = 24; loc = j - 16384; }
      else if (j < 98304) { src = 10; loc = j - 32768; }
      else                { src = 12; loc = j - 98304; }
      const void* sp = ip.p[src];
      unsigned short* wb = (unsigned short*)(ws + WB_OFF);
      wb[j] = f32 ? f2bf(((const float*)sp)[loc]) : ((const unsigned short*)sp)[loc];
    }
  }
}

// ===== fused main (VERBATIM Round-2 verified <90.5us): node 48 blocks + edge 768 =====
union SMem {
  struct {
    unsigned short A0[32][CZ + 8];
    unsigned short A1[32][CZ + 8];
    float O[32][CZ + 4];
    int J[NN];
    float Red[32][8];
    float RedQ[32][8];
    float Mu[32];
    float Rs[32];
  } e;
  struct {
    unsigned short A0[16][CS + 8];
    unsigned short A1[16][CS + 8];
    float O[16][CS + 4];
    float Red[16][16];
    float RedQ[16][16];
    float Mu[16];
    float Rs[16];
  } n;
};

__global__ __launch_bounds__(256) void main_mfma(const int* __restrict__ seq_idx,
                                                 const float* __restrict__ ws,
                                                 const void* __restrict__ fmraw,
                                                 void* __restrict__ outv) {
  __shared__ __align__(16) SMem sm;
  const int t = threadIdx.x;
  const int wave = t >> 6, lane = t & 63, quad = lane >> 4, l16 = lane & 15;
  const float* P2 = ws + P2_OFF;
  const unsigned short* WB = (const unsigned short*)(ws + WB_OFF);
  const bool f32o = probe_f32(fmraw);

  if (blockIdx.x < NODE_BLKS) {
    const int row0 = blockIdx.x * 16;
    const unsigned short* W1 = WB + UB_WN1;
    const unsigned short* W2 = WB + UB_WN2;
    const float* seq0 = ws + SEQ0_OFF;
#pragma unroll
    for (int r = 0; r < 16; ++r)
      sm.n.A0[r][t] = f2bf(fmaxf(seq0[(row0 + r) * CS + t], 0.0f));
    __syncthreads();
    short8 af[8];
    floatx4 acc[4];
#pragma unroll
    for (int ks = 0; ks < 8; ++ks) af[ks] = *(const short8*)&sm.n.A0[l16][ks * 32 + quad * 8];
#pragma unroll
    for (int n = 0; n < 4; ++n) acc[n] = (floatx4){0.f, 0.f, 0.f, 0.f};
#pragma unroll
    for (int ntl = 0; ntl < 4; ++ntl) {
      const int n0 = wave * 64 + ntl * 16;
#pragma unroll
      for (int ks = 0; ks < 8; ++ks) {
        short8 bfr = *(const short8*)&W1[(n0 + l16) * CS + ks * 32 + quad * 8];
        acc[ntl] = __builtin_amdgcn_mfma_f32_16x16x32_bf16(af[ks], bfr, acc[ntl], 0, 0, 0);
      }
    }
#pragma unroll
    for (int ntl = 0; ntl < 4; ++ntl) {
      const int n0 = wave * 64 + ntl * 16;
      const float b1v = P2[qBN1 + n0 + l16];
#pragma unroll
      for (int i = 0; i < 4; ++i)
        sm.n.A1[quad * 4 + i][n0 + l16] = f2bf(fmaxf(acc[ntl][i] + b1v, 0.0f));
    }
    __syncthreads();
#pragma unroll
    for (int ks = 0; ks < 8; ++ks) af[ks] = *(const short8*)&sm.n.A1[l16][ks * 32 + quad * 8];
#pragma unroll
    for (int n = 0; n < 4; ++n) acc[n] = (floatx4){0.f, 0.f, 0.f, 0.f};
#pragma unroll
    for (int ntl = 0; ntl < 4; ++ntl) {
      const int n0 = wave * 64 + ntl * 16;
#pragma unroll
      for (int ks = 0; ks < 8; ++ks) {
        short8 bfr = *(const short8*)&W2[(n0 + l16) * CS + ks * 32 + quad * 8];
        acc[ntl] = __builtin_amdgcn_mfma_f32_16x16x32_bf16(af[ks], bfr, acc[ntl], 0, 0, 0);
      }
    }
#pragma unroll
    for (int ntl = 0; ntl < 4; ++ntl) {
      const int n0 = wave * 64 + ntl * 16;
      const float b2v = P2[qBN2 + n0 + l16];
#pragma unroll
      for (int i = 0; i < 4; ++i)
        sm.n.O[quad * 4 + i][n0 + l16] = acc[ntl][i] + b2v;
    }
    __syncthreads();
    {
      const int r = t >> 4, seg = t & 15;
      float s = 0.f, q = 0.f;
#pragma unroll
      for (int k = 0; k < 16; ++k) { float v = sm.n.O[r][seg * 16 + k]; s += v; q += v * v; }
      sm.n.Red[r][seg] = s;
      sm.n.RedQ[r][seg] = q;
    }
    __syncthreads();
    if (t < 16) {
      float s = 0.f, q = 0.f;
#pragma unroll
      for (int k = 0; k < 16; ++k) { s += sm.n.Red[t][k]; q += sm.n.RedQ[t][k]; }
      float mu = s * (1.0f / CS);
      float var = q * (1.0f / CS) - mu * mu;
      sm.n.Mu[t] = mu;
      sm.n.Rs[t] = rsqrtf(var + 1e-5f);
    }
    __syncthreads();
    {
      const float g = P2[qGN + t], be = P2[qBEN + t];
      if (f32o) {
        float* o = (float*)outv;
#pragma unroll
        for (int r = 0; r < 16; ++r)
          o[(size_t)(row0 + r) * CS + t] = (sm.n.O[r][t] - sm.n.Mu[r]) * sm.n.Rs[r] * g + be;
      } else {
        bf16* o = (bf16*)outv;
#pragma unroll
        for (int r = 0; r < 16; ++r)
          o[(size_t)(row0 + r) * CS + t] =
              __float2bfloat16((sm.n.O[r][t] - sm.n.Mu[r]) * sm.n.Rs[r] * g + be);
      }
    }
    return;
  }

  const int eb = blockIdx.x - NODE_BLKS;
  const int irow = eb % NN, b = eb / NN;
  const unsigned short* W1 = WB + UB_WE1;
  const unsigned short* W2 = WB + UB_WE2;
  const float* tab = ws + TAB_OFF;
  const float* eL = ws + EL_OFF;
  const float* eR = ws + ER_OFF;
  short8 w1f[2][4], w2f[2][4];
  float b1v[2], b2v[2];
#pragma unroll
  for (int ntl = 0; ntl < 2; ++ntl) {
    const int n0 = (wave * 2 + ntl) * 16;
    b1v[ntl] = P2[qBE1 + n0 + l16];
    b2v[ntl] = P2[qBE2 + n0 + l16];
#pragma unroll
    for (int ks = 0; ks < 4; ++ks) {
      w1f[ntl][ks] = *(const short8*)&W1[(n0 + l16) * CZ + ks * 32 + quad * 8];
      w2f[ntl][ks] = *(const short8*)&W2[(n0 + l16) * CZ + ks * 32 + quad * 8];
    }
  }
  for (int k = t; k < NN; k += 256) sm.e.J[k] = seq_idx[b * NN + k];
  const int idx_i = seq_idx[b * NN + irow];
  const int c4 = (t & 31) * 4;
  const int rg = t >> 5;
  const floatx4 eLv = *(const floatx4*)&eL[(b * NN + irow) * CZ + c4];
  const int cw = t & 127;
  const float gv = P2[qGE + cw], bev = P2[qBEE + cw];
  const size_t base0 = ((size_t)(b * NN + irow) * NN) * CZ;

  for (int jt = 0; jt < NN / 32; ++jt) {
    const int j0 = jt * 32;
    __syncthreads();
#pragma unroll
    for (int rr = 0; rr < 4; ++rr) {
      const int r = rg + rr * 8;
      int rel = idx_i - sm.e.J[j0 + r] + 1024;
      rel = min(max(rel, 0), 2047);
      const floatx4 tv = *(const floatx4*)&tab[rel * CZ + c4];
      const floatx4 ev = *(const floatx4*)&eR[(b * NN + j0 + r) * CZ + c4];
      short4v sv;
      sv[0] = (short)f2bf(fmaxf(tv[0] + ev[0] + eLv[0], 0.0f));
      sv[1] = (short)f2bf(fmaxf(tv[1] + ev[1] + eLv[1], 0.0f));
      sv[2] = (short)f2bf(fmaxf(tv[2] + ev[2] + eLv[2], 0.0f));
      sv[3] = (short)f2bf(fmaxf(tv[3] + ev[3] + eLv[3], 0.0f));
      *(short4v*)&sm.e.A0[r][c4] = sv;
    }
    __syncthreads();
    short8 af[2][4];
    floatx4 acc[2][2];
#pragma unroll
    for (int mt = 0; mt < 2; ++mt)
#pragma unroll
      for (int ks = 0; ks < 4; ++ks)
        af[mt][ks] = *(const short8*)&sm.e.A0[mt * 16 + l16][ks * 32 + quad * 8];
#pragma unroll
    for (int mt = 0; mt < 2; ++mt)
#pragma unroll
      for (int n = 0; n < 2; ++n) acc[mt][n] = (floatx4){0.f, 0.f, 0.f, 0.f};
#pragma unroll
    for (int ntl = 0; ntl < 2; ++ntl)
#pragma unroll
      for (int ks = 0; ks < 4; ++ks) {
        acc[0][ntl] = __builtin_amdgcn_mfma_f32_16x16x32_bf16(af[0][ks], w1f[ntl][ks], acc[0][ntl], 0, 0, 0);
        acc[1][ntl] = __builtin_amdgcn_mfma_f32_16x16x32_bf16(af[1][ks], w1f[ntl][ks], acc[1][ntl], 0, 0, 0);
      }
#pragma unroll
    for (int ntl = 0; ntl < 2; ++ntl) {
      const int n0 = (wave * 2 + ntl) * 16;
#pragma unroll
      for (int mt = 0; mt < 2; ++mt)
#pragma unroll
        for (int i = 0; i < 4; ++i)
          sm.e.A1[mt * 16 + quad * 4 + i][n0 + l16] = f2bf(fmaxf(acc[mt][ntl][i] + b1v[ntl], 0.0f));
    }
    __syncthreads();
#pragma unroll
    for (int mt = 0; mt < 2; ++mt)
#pragma unroll
      for (int ks = 0; ks < 4; ++ks)
        af[mt][ks] = *(const short8*)&sm.e.A1[mt * 16 + l16][ks * 32 + quad * 8];
#pragma unroll
    for (int mt = 0; mt < 2; ++mt)
#pragma unroll
      for (int n = 0; n < 2; ++n) acc[mt][n] = (floatx4){0.f, 0.f, 0.f, 0.f};
#pragma unroll
    for (int ntl = 0; ntl < 2; ++ntl)
#pragma unroll
      for (int ks = 0; ks < 4; ++ks) {
        acc[0][ntl] = __builtin_amdgcn_mfma_f32_16x16x32_bf16(af[0][ks], w2f[ntl][ks], acc[0][ntl], 0, 0, 0);
        acc[1][ntl] = __builtin_amdgcn_mfma_f32_16x16x32_bf16(af[1][ks], w2f[ntl][ks], acc[1][ntl], 0, 0, 0);
      }
#pragma unroll
    for (int ntl = 0; ntl < 2; ++ntl) {
      const int n0 = (wave * 2 + ntl) * 16;
#pragma unroll
      for (int mt = 0; mt < 2; ++mt)
#pragma unroll
        for (int i = 0; i < 4; ++i)
          sm.e.O[mt * 16 + quad * 4 + i][n0 + l16] = acc[mt][ntl][i] + b2v[ntl];
    }
    __syncthreads();
    {
      const int r = t >> 3, seg = t & 7;
      float s = 0.f, q = 0.f;
#pragma unroll
      for (int k = 0; k < 16; ++k) { float v = sm.e.O[r][seg * 16 + k]; s += v; q += v * v; }
      sm.e.Red[r][seg] = s;
      sm.e.RedQ[r][seg] = q;
    }
    __syncthreads();
    if (t < 32) {
      float s = 0.f, q = 0.f;
#pragma unroll
      for (int k = 0; k < 8; ++k) { s += sm.e.Red[t][k]; q += sm.e.RedQ[t][k]; }
      float mu = s * (1.0f / CZ);
      float var = q * (1.0f / CZ) - mu * mu;
      sm.e.Mu[t] = mu;
      sm.e.Rs[t] = rsqrtf(var + 1e-5f);
    }
    __syncthreads();
    {
      const int rh = (t >> 7) * 16;
      const size_t base = base0 + (size_t)j0 * CZ + cw;
      if (f32o) {
        float* o = (float*)outv + (size_t)BB * NN * CS;
#pragma unroll
        for (int rr = 0; rr < 16; ++rr) {
          const int r = rh + rr;
          o[base + (size_t)r * CZ] = (sm.e.O[r][cw] - sm.e.Mu[r]) * sm.e.Rs[r] * gv + bev;
        }
      } else {
        bf16* o = (bf16*)outv + (size_t)BB * NN * CS;
#pragma unroll
        for (int rr = 0; rr < 16; ++rr) {
          const int r = rh + rr;
          o[base + (size_t)r * CZ] =
              __float2bfloat16((sm.e.O[r][cw] - sm.e.Mu[r]) * sm.e.Rs[r] * gv + bev);
        }
      }
    }
  }
}

extern "C" void kernel_launch(void* const* d_in, const int* in_sizes, int n_in,
                              void* d_out, int out_size, void* d_ws, size_t ws_size,
                              hipStream_t stream) {
  (void)in_sizes; (void)n_in; (void)out_size; (void)ws_size;
  const int* seq_idx = (const int*)d_in[0];
  float* ws = (float*)d_ws;
  InPtrs ip;
  for (int i = 0; i < 28; ++i) ip.p[i] = d_in[i];
  hipLaunchKernelGGL(prep, dim3(NODE8_BLKS + TAB_BLKS + CVT_BLKS), dim3(256), 0, stream,
                     ip, seq_idx, ws);
  hipLaunchKernelGGL(main_mfma, dim3(NODE_BLKS + BB * NN), dim3(256), 0, stream,
                     seq_idx, ws, d_in[3], d_out);
}